// Round 6
// baseline (322.995 us; speedup 1.0000x reference)
//
#include <hip/hip_runtime.h>
#include <hip/hip_bf16.h>

typedef __attribute__((ext_vector_type(8)))  short          bf16x8;
typedef __attribute__((ext_vector_type(16))) float          f32x16;
typedef __attribute__((ext_vector_type(8)))  unsigned short u16x8;

#define N_EMB 200000
#define K_C   512
#define D_DIM 128
#define TPB   10            // 32-n tiles per block; 6250 = 625 x 10, exact
#define NGRPS 625
#define BUFB  16384         // per LDS buffer: hi 8192 + lo 8192 (16 d-groups, no fold)
#define LOOFF 8192
#define MINOFF 32768        // minarr u32[320]
#define C2OFF  34048        // c2tab f32[256]
#define X2OFF  35072        // x2tab f32[2][32]
#define LDS_TOTAL 35328

// ws layout (bytes):
//   0        pack u64[512]        (4096)
//   4096     c2ws f32[512]        (2048)   -> 6144
//   6144     hiA u16[512*128]     (131072) -> 137216
//   137216   loA u16[512*128]     (131072) -> 268288
//   268288   minA u32[200000]     (800000) -> 1068288
//   1068288  minB u32[200000]     (800000) -> 1868288
//   1868288  lossPartial f32[391]

__device__ __forceinline__ unsigned short bf16_bits(float x) {
    __hip_bfloat16 h = __float2bfloat16(x);
    return *reinterpret_cast<unsigned short*>(&h);
}
__device__ __forceinline__ float bf16_val(unsigned short b) {
    unsigned u = (unsigned)b << 16;
    return __uint_as_float(u);
}

// LDS 16B-block index: group-major, XOR swizzle, proven conflict-free (R4/R5: 0 conflicts).
__device__ __forceinline__ int BLK(int g, int n) { return (g << 5) | (n ^ (g & 7)); }

__global__ void init_kernel(const float* __restrict__ centers,
                            unsigned short* __restrict__ hiA,
                            unsigned short* __restrict__ loA,
                            float* __restrict__ c2ws,
                            unsigned long long* __restrict__ pack) {
    const int t = threadIdx.x, w = t >> 6, l = t & 63;
    const int k = blockIdx.x * 8 + w;            // 64 blocks x 8 waves = 512 rows
    const float2 c = *reinterpret_cast<const float2*>(centers + k * D_DIM + 2 * l);
    float c2 = c.x * c.x + c.y * c.y;
#pragma unroll
    for (int off = 1; off < 64; off <<= 1) c2 += __shfl_xor(c2, off);

    float v0 = -2.f * c.x, v1 = -2.f * c.y;
    unsigned short h0 = bf16_bits(v0); unsigned short l0 = bf16_bits(v0 - bf16_val(h0));
    unsigned short h1 = bf16_bits(v1); unsigned short l1 = bf16_bits(v1 - bf16_val(h1));
    *reinterpret_cast<ushort2*>(hiA + k * D_DIM + 2 * l) = make_ushort2(h0, h1);
    *reinterpret_cast<ushort2*>(loA + k * D_DIM + 2 * l) = make_ushort2(l0, l1);

    if (l == 0) c2ws[k] = c2;
    if (l == 1) pack[k] = 0xFFFFFFFFFFFFFFFFULL;
}

__launch_bounds__(512, 4)   // 4 waves/EU => 16 waves/CU => 2 x 8-wave blocks resident
__global__ void cluster_mfma(const float* __restrict__ embs,
                             const unsigned short* __restrict__ hiA,
                             const unsigned short* __restrict__ loA,
                             const float* __restrict__ c2ws,
                             unsigned long long* __restrict__ pack,
                             unsigned* __restrict__ minA,
                             unsigned* __restrict__ minB) {
    __shared__ __align__(16) char lds_c[LDS_TOTAL];
    unsigned* minarr = reinterpret_cast<unsigned*>(lds_c + MINOFF);
    float*    c2tab  = reinterpret_cast<float*>(lds_c + C2OFF);
    float*    x2tab  = reinterpret_cast<float*>(lds_c + X2OFF);

    const int t = threadIdx.x, w = t >> 6, l = t & 63;
    const int col = l & 31, half = l >> 5;
    const int kside = blockIdx.x & 1, ngrp = blockIdx.x >> 1;
    const int kbase = kside * 256 + w * 32;
    const int myk = kbase + col;
    const int srow = t >> 4, schunk = t & 15;
    const int tbase = ngrp * TPB;

    // ---- A fragments: 8 hi + 8 lo (no fold rows) = 64 VGPRs ----
    bf16x8 a_hi[8], a_lo[8];
    {
        const unsigned short* hrow = hiA + myk * D_DIM + 8 * half;
        const unsigned short* lrow = loA + myk * D_DIM + 8 * half;
#pragma unroll
        for (int s = 0; s < 8; ++s) {
            a_hi[s] = *reinterpret_cast<const bf16x8*>(hrow + 16 * s);
            a_lo[s] = *reinterpret_cast<const bf16x8*>(lrow + 16 * s);
        }
    }

    if (t < 256) c2tab[t] = c2ws[kside * 256 + t];
    if (t < TPB * 32) minarr[t] = 0xFFFFFFFFu;

    float best_d[16];
#pragma unroll
    for (int r = 0; r < 16; ++r) best_d[r] = 3.4e38f;
    unsigned nib0 = 0u, nib1 = 0u;   // 16 x 4-bit best-tile indices

    // preload tile 0
    float vcur[8];
    {
        const float* erow = embs + (tbase * 32 + srow) * D_DIM + schunk * 8;
        float4 u0 = *reinterpret_cast<const float4*>(erow);
        float4 u1 = *reinterpret_cast<const float4*>(erow + 4);
        vcur[0] = u0.x; vcur[1] = u0.y; vcur[2] = u0.z; vcur[3] = u0.w;
        vcur[4] = u1.x; vcur[5] = u1.y; vcur[6] = u1.z; vcur[7] = u1.w;
    }

    for (int tl = 0; tl < TPB; ++tl) {
        char* buf = lds_c + (tl & 1) * BUFB;
        const int slot = (tl & 1) * 32;

        // prefetch next tile into regs (consumed next iteration; rides across barrier)
        float vnx[8];
        {
            const int tn = (tl < TPB - 1) ? tl + 1 : tl;
            const float* erow = embs + ((tbase + tn) * 32 + srow) * D_DIM + schunk * 8;
            float4 u0 = *reinterpret_cast<const float4*>(erow);
            float4 u1 = *reinterpret_cast<const float4*>(erow + 4);
            vnx[0] = u0.x; vnx[1] = u0.y; vnx[2] = u0.z; vnx[3] = u0.w;
            vnx[4] = u1.x; vnx[5] = u1.y; vnx[6] = u1.z; vnx[7] = u1.w;
        }

        // convert current tile -> LDS hi/lo + x2 row sums
        {
            float x2p = 0.f;
            u16x8 hv, lv;
#pragma unroll
            for (int i = 0; i < 8; ++i) {
                float v = vcur[i];
                x2p = fmaf(v, v, x2p);
                unsigned short hb = bf16_bits(v);
                unsigned short lb = bf16_bits(v - bf16_val(hb));
                hv[i] = hb; lv[i] = lb;
            }
            const int wb = BLK(schunk, srow);
            *reinterpret_cast<u16x8*>(buf + (wb << 4)) = hv;
            *reinterpret_cast<u16x8*>(buf + LOOFF + (wb << 4)) = lv;
            float x2 = x2p;
#pragma unroll
            for (int off = 1; off < 16; off <<= 1) x2 += __shfl_xor(x2, off);
            if (schunk == 0) x2tab[slot + srow] = x2;
        }
        asm volatile("s_waitcnt lgkmcnt(0)" ::: "memory");
        __builtin_amdgcn_s_barrier();

        // MFMA: 8 steps x 3 passes = 24; acc = -2 x.c (dot part only)
        f32x16 acc;
#pragma unroll
        for (int r = 0; r < 16; ++r) acc[r] = 0.f;
#pragma unroll
        for (int s = 0; s < 8; ++s) {
            const int gg = 2 * s + half;
            const char* pb = buf + (BLK(gg, col) << 4);
            bf16x8 bh = *reinterpret_cast<const bf16x8*>(pb);
            bf16x8 bl = *reinterpret_cast<const bf16x8*>(pb + LOOFF);
            acc = __builtin_amdgcn_mfma_f32_32x32x16_bf16(a_hi[s], bh, acc, 0, 0, 0);
            acc = __builtin_amdgcn_mfma_f32_32x32x16_bf16(a_hi[s], bl, acc, 0, 0, 0);
            acc = __builtin_amdgcn_mfma_f32_32x32x16_bf16(a_lo[s], bh, acc, 0, 0, 0);
        }

        // epilogue: x2 via LDS (per-n), c2 via uniform LDS broadcast (per-k)
        const float x2c = x2tab[slot + col];
        const float* c2b = c2tab + w * 32 + 4 * half;
        float m = 3.4e38f;
        const unsigned tlu = (unsigned)tl;
#pragma unroll
        for (int r = 0; r < 16; ++r) {
            const float c2k = c2b[(r & 3) + 8 * (r >> 2)];
            m = fminf(m, acc[r] + c2k);                    // loss path (c2 in, x2 later)
            const float drep = acc[r] + x2c;               // rep path (x2 in, c2 const/k)
            const bool better = drep < best_d[r];
            best_d[r] = better ? drep : best_d[r];
            const int sh = 4 * (r & 7);
            if (r < 8) nib0 = better ? ((nib0 & ~(0xFu << sh)) | (tlu << sh)) : nib0;
            else       nib1 = better ? ((nib1 & ~(0xFu << sh)) | (tlu << sh)) : nib1;
        }
        m = fminf(m, __shfl_xor(m, 32));
        if (l < 32) atomicMin(&minarr[tl * 32 + col], __float_as_uint(m + x2c));

#pragma unroll
        for (int i = 0; i < 8; ++i) vcur[i] = vnx[i];
    }
    __syncthreads();

    // per-n mins: plain store per kside
    if (t < TPB * 32) {
        unsigned* dst = kside ? minB : minA;
        dst[ngrp * (TPB * 32) + t] = minarr[t];
    }

    // rep: reconstruct n, cross-lane lexicographic argmin within each 32-lane half,
    // then global packed atomicMin (+1024 bias keeps the float field non-negative).
#pragma unroll
    for (int r = 0; r < 16; ++r) {
        float d = best_d[r];
        const unsigned nib = ((r < 8 ? nib0 : nib1) >> (4 * (r & 7))) & 0xFu;
        unsigned n = (unsigned)((tbase + (int)nib) * 32 + col);
        for (int off = 16; off >= 1; off >>= 1) {
            float od = __shfl_xor(d, off);
            unsigned on = __shfl_xor(n, off);
            bool take = (od < d) || (od == d && on < n);
            d = take ? od : d;
            n = take ? on : n;
        }
        if (col == 0) {
            int k = kbase + (r & 3) + 8 * (r >> 2) + 4 * half;
            unsigned long long p =
                ((unsigned long long)__float_as_uint(d + 1024.f) << 32) |
                (unsigned long long)n;
            atomicMin(&pack[k], p);
        }
    }
}

__global__ void finalize1(const float* __restrict__ centers,
                          const unsigned long long* __restrict__ pack,
                          const unsigned* __restrict__ minA,
                          const unsigned* __restrict__ minB,
                          float* __restrict__ lossPartial,
                          float* __restrict__ out) {
    __shared__ float wsum[8];
    const int t = threadIdx.x, wv = t >> 6, ln = t & 63;
    const int gid = blockIdx.x * 512 + t;
    if (gid < 16384)
        reinterpret_cast<float4*>(out)[gid] =
            reinterpret_cast<const float4*>(centers)[gid];
    if (gid < K_C)
        out[65536 + gid] = (float)(unsigned)(pack[gid] & 0xFFFFFFFFu);
    float s = 0.f;
    if (gid < N_EMB) {
        float m = fminf(__uint_as_float(minA[gid]), __uint_as_float(minB[gid]));
        s = sqrtf(fmaxf(m, 1e-12f));
    }
#pragma unroll
    for (int off = 1; off < 64; off <<= 1) s += __shfl_xor(s, off);
    if (ln == 0) wsum[wv] = s;
    __syncthreads();
    if (t == 0) {
        float tot = 0.f;
#pragma unroll
        for (int i = 0; i < 8; ++i) tot += wsum[i];
        lossPartial[blockIdx.x] = tot;   // plain store — no global atomics
    }
}

__global__ void finalize2(const float* __restrict__ lossPartial,
                          float* __restrict__ out) {
    __shared__ float wsum[8];
    const int t = threadIdx.x, wv = t >> 6, ln = t & 63;
    float s = (t < 391) ? lossPartial[t] : 0.f;
#pragma unroll
    for (int off = 1; off < 64; off <<= 1) s += __shfl_xor(s, off);
    if (ln == 0) wsum[wv] = s;
    __syncthreads();
    if (t == 0) {
        float tot = 0.f;
#pragma unroll
        for (int i = 0; i < 8; ++i) tot += wsum[i];
        out[65536 + K_C] = tot;
    }
}

extern "C" void kernel_launch(void* const* d_in, const int* in_sizes, int n_in,
                              void* d_out, int out_size, void* d_ws, size_t ws_size,
                              hipStream_t stream) {
    const float* embs    = (const float*)d_in[0];
    const float* centers = (const float*)d_in[1];
    float* out = (float*)d_out;

    unsigned long long* pack = (unsigned long long*)d_ws;
    float* c2ws = (float*)((char*)d_ws + 4096);
    unsigned short* hiA = (unsigned short*)((char*)d_ws + 6144);
    unsigned short* loA = (unsigned short*)((char*)d_ws + 137216);
    unsigned* minA = (unsigned*)((char*)d_ws + 268288);
    unsigned* minB = (unsigned*)((char*)d_ws + 1068288);
    float* lossPartial = (float*)((char*)d_ws + 1868288);

    init_kernel<<<64, 512, 0, stream>>>(centers, hiA, loA, c2ws, pack);
    cluster_mfma<<<NGRPS * 2, 512, 0, stream>>>(embs, hiA, loA, c2ws, pack, minA, minB);
    finalize1<<<391, 512, 0, stream>>>(centers, pack, minA, minB, lossPartial, out);
    finalize2<<<1, 512, 0, stream>>>(lossPartial, out);
}

// Round 7
// 264.811 us; speedup vs baseline: 1.2197x; 1.2197x over previous
//
#include <hip/hip_runtime.h>
#include <hip/hip_bf16.h>

typedef __attribute__((ext_vector_type(8)))  short          bf16x8;
typedef __attribute__((ext_vector_type(16))) float          f32x16;
typedef __attribute__((ext_vector_type(8)))  unsigned short u16x8;

#define N_EMB 200000
#define K_C   512
#define D_DIM 128
#define TPB   10            // tiles per block; 6250 = 625 x 10 exact
#define NGRPS 625
#define AROW  144           // hiA row: 128 data + 8 fold + 8 zero
#define TILEB 16384         // staged tile bytes: 16 g x {hi,lo} x 32 n x 16 B
#define MINOFF 32768        // minarr after 2 buffers

// ws layout (bytes):
//   0        pack u64[512]        (4096)
//   4096     hiA u16[512*144]     (147456) -> 151552
//   151552   loA u16[512*128]     (131072) -> 282624
//   282624   x2g f32[200000]      (800000) -> 1082624
//   1082624  minA u32[200000]     (800000) -> 1882624
//   1882624  minB u32[200000]     (800000) -> 2682624
//   2682624  lossPartial f32[391]

__device__ __forceinline__ unsigned short bf16_bits(float x) {
    __hip_bfloat16 h = __float2bfloat16(x);
    return *reinterpret_cast<unsigned short*>(&h);
}
__device__ __forceinline__ float bf16_val(unsigned short b) {
    unsigned u = (unsigned)b << 16;
    return __uint_as_float(u);
}

__device__ __forceinline__ void gload_lds16(const void* g, void* l) {
    __builtin_amdgcn_global_load_lds(
        (const __attribute__((address_space(1))) unsigned int*)g,
        (__attribute__((address_space(3))) unsigned int*)l, 16, 0, 0);
}

// ---- pre-pass: convert embs (f32) -> fragment-ordered bf16 hi/lo, IN PLACE ----
// tile T bytes [T*16384, +16384): layout [g 0..15][hl 0..1][n 0..31][16 B]
__global__ void prep_b(float* __restrict__ embs_rw, float* __restrict__ x2g) {
    const int T = blockIdx.x, t = threadIdx.x;
    const int n = t >> 4, g = t & 15;
    float* base = embs_rw + (size_t)T * 32 * D_DIM;
    float4 u0, u1;
    {
        const float* src = base + n * D_DIM + 8 * g;
        u0 = *reinterpret_cast<const float4*>(src);
        u1 = *reinterpret_cast<const float4*>(src + 4);
    }
    __syncthreads();   // all reads of this tile complete before any write
    float v[8] = {u0.x, u0.y, u0.z, u0.w, u1.x, u1.y, u1.z, u1.w};
    float x2p = 0.f;
    u16x8 hv, lv;
#pragma unroll
    for (int i = 0; i < 8; ++i) {
        x2p = fmaf(v[i], v[i], x2p);
        unsigned short hb = bf16_bits(v[i]);
        unsigned short lb = bf16_bits(v[i] - bf16_val(hb));
        hv[i] = hb; lv[i] = lb;
    }
    unsigned short* ob = reinterpret_cast<unsigned short*>(base);
    *reinterpret_cast<u16x8*>(ob + g * 512 + n * 8)       = hv;  // byte g*1024 + n*16
    *reinterpret_cast<u16x8*>(ob + g * 512 + 256 + n * 8) = lv;  // +512 B
#pragma unroll
    for (int off = 1; off < 16; off <<= 1) x2p += __shfl_xor(x2p, off);
    if (g == 0) x2g[T * 32 + n] = x2p;
}

// ---- A prep: (-2c) hi/lo frags + c2 fold row {c2h,c2l,e2c} ----
__global__ void init_kernel(const float* __restrict__ centers,
                            unsigned short* __restrict__ hiA,
                            unsigned short* __restrict__ loA,
                            unsigned long long* __restrict__ pack) {
    const int t = threadIdx.x, w = t >> 6, l = t & 63;
    const int k = blockIdx.x * 8 + w;
    const float2 c = *reinterpret_cast<const float2*>(centers + k * D_DIM + 2 * l);
    float c2 = c.x * c.x + c.y * c.y;
#pragma unroll
    for (int off = 1; off < 64; off <<= 1) c2 += __shfl_xor(c2, off);

    float v0 = -2.f * c.x, v1 = -2.f * c.y;
    unsigned short h0 = bf16_bits(v0); unsigned short l0 = bf16_bits(v0 - bf16_val(h0));
    unsigned short h1 = bf16_bits(v1); unsigned short l1 = bf16_bits(v1 - bf16_val(h1));
    *reinterpret_cast<ushort2*>(hiA + k * AROW + 2 * l) = make_ushort2(h0, h1);
    *reinterpret_cast<ushort2*>(loA + k * D_DIM + 2 * l) = make_ushort2(l0, l1);

    if (l == 0) {
        unsigned short c2h = bf16_bits(c2);
        float c2hf = bf16_val(c2h);
        unsigned short c2l = bf16_bits(c2 - c2hf);
        float c2lf = bf16_val(c2l);
        unsigned short e2c = bf16_bits(c2 - c2hf - c2lf);
        u16x8 a, z;
#pragma unroll
        for (int i = 0; i < 8; ++i) { a[i] = 0; z[i] = 0; }
        a[0] = c2h; a[1] = c2l; a[2] = e2c;
        *reinterpret_cast<u16x8*>(hiA + k * AROW + 128) = a;
        *reinterpret_cast<u16x8*>(hiA + k * AROW + 136) = z;
    }
    if (l == 1) pack[k] = 0xFFFFFFFFFFFFFFFFULL;
}

__launch_bounds__(512, 4)   // 16 waves/CU = 2 blocks resident
__global__ void cluster_mfma(const float* __restrict__ embs_conv,
                             const unsigned short* __restrict__ hiA,
                             const unsigned short* __restrict__ loA,
                             const float* __restrict__ x2g,
                             unsigned long long* __restrict__ pack,
                             unsigned* __restrict__ minA,
                             unsigned* __restrict__ minB) {
    __shared__ __align__(16) char lds_c[2 * TILEB + TPB * 32 * 4];
    unsigned* minarr = reinterpret_cast<unsigned*>(lds_c + MINOFF);
    const char* hlB = reinterpret_cast<const char*>(embs_conv);

    const int t = threadIdx.x, w = t >> 6, l = t & 63;
    const int col = l & 31, half = l >> 5;
    const int kside = blockIdx.x & 1, ngrp = blockIdx.x >> 1;
    const int kbase = kside * 256 + w * 32;
    const int myk = kbase + col;
    const int tbase = ngrp * TPB;

    // A: 8 hi + 8 lo + fold-hi (4 regs) + const ones-B (4 regs)
    bf16x8 a_hi[8], a_lo[8], afold, bones;
    {
        const unsigned short* hrow = hiA + myk * AROW + 8 * half;
        const unsigned short* lrow = loA + myk * D_DIM + 8 * half;
#pragma unroll
        for (int s = 0; s < 8; ++s) {
            a_hi[s] = *reinterpret_cast<const bf16x8*>(hrow + 16 * s);
            a_lo[s] = *reinterpret_cast<const bf16x8*>(lrow + 16 * s);
        }
        afold = *reinterpret_cast<const bf16x8*>(hiA + myk * AROW + 128 + 8 * half);
#pragma unroll
        for (int i = 0; i < 8; ++i)
            bones[i] = (half == 0 && i < 3) ? (short)0x3F80 : (short)0;
    }

    float best_d[16];
#pragma unroll
    for (int r = 0; r < 16; ++r) best_d[r] = 3.4e38f;
    unsigned nib0 = 0u, nib1 = 0u;

    if (t < TPB * 32) minarr[t] = 0xFFFFFFFFu;

    // stage tile 0 (2 DMA issues per wave, 1 KB each)
    {
        const char* src = hlB + (size_t)(tbase + 0) * TILEB;
        char* dst = lds_c;
#pragma unroll
        for (int j = 0; j < 2; ++j) {
            const int off = ((w * 2 + j) << 10) + (l << 4);
            gload_lds16(src + off, dst + off);
        }
    }

    for (int tl = 0; tl < TPB; ++tl) {
        char* buf = lds_c + (tl & 1) * TILEB;

        // x2 for current tile (issued BEFORE next-stage so vmcnt counting holds)
        const float x2c = x2g[(tbase + tl) * 32 + col];

        if (tl < TPB - 1) {
            const char* src = hlB + (size_t)(tbase + tl + 1) * TILEB;
            char* dst = lds_c + ((tl + 1) & 1) * TILEB;
#pragma unroll
            for (int j = 0; j < 2; ++j) {
                const int off = ((w * 2 + j) << 10) + (l << 4);
                gload_lds16(src + off, dst + off);
            }
            // queue: [st(t) x2, x2c, st(t+1) x2] -> drain st(t) only
            asm volatile("s_waitcnt vmcnt(3)" ::: "memory");
        } else {
            asm volatile("s_waitcnt vmcnt(1)" ::: "memory");
        }
        __builtin_amdgcn_s_barrier();

        // 25 MFMA: 8 steps x 3 passes + c2-fold
        f32x16 acc;
#pragma unroll
        for (int r = 0; r < 16; ++r) acc[r] = 0.f;
#pragma unroll
        for (int s = 0; s < 8; ++s) {
            const char* pb = buf + ((2 * s + half) << 10) + (col << 4);
            bf16x8 bh = *reinterpret_cast<const bf16x8*>(pb);
            bf16x8 bl = *reinterpret_cast<const bf16x8*>(pb + 512);
            acc = __builtin_amdgcn_mfma_f32_32x32x16_bf16(a_hi[s], bh, acc, 0, 0, 0);
            acc = __builtin_amdgcn_mfma_f32_32x32x16_bf16(a_hi[s], bl, acc, 0, 0, 0);
            acc = __builtin_amdgcn_mfma_f32_32x32x16_bf16(a_lo[s], bh, acc, 0, 0, 0);
        }
        acc = __builtin_amdgcn_mfma_f32_32x32x16_bf16(afold, bones, acc, 0, 0, 0);
        // acc = c2[k] - 2 x.c ; d2 = acc + x2[n]

        // loss: min over this wave's 32 k for col
        float m = acc[0];
#pragma unroll
        for (int r = 1; r < 16; ++r) m = fminf(m, acc[r]);
        m = fminf(m, __shfl_xor(m, 32));
        if (l < 32) atomicMin(&minarr[tl * 32 + col], __float_as_uint(m + x2c));

        // rep: per-(lane,reg) running best, 4-bit tile index
        const unsigned tlu = (unsigned)tl;
#pragma unroll
        for (int r = 0; r < 16; ++r) {
            const float drep = acc[r] + x2c;
            const bool better = drep < best_d[r];
            best_d[r] = better ? drep : best_d[r];
            const int sh = 4 * (r & 7);
            if (r < 8) nib0 = better ? ((nib0 & ~(0xFu << sh)) | (tlu << sh)) : nib0;
            else       nib1 = better ? ((nib1 & ~(0xFu << sh)) | (tlu << sh)) : nib1;
        }
        __builtin_amdgcn_s_barrier();   // all reads of buf done before its restage
    }
    __syncthreads();

    if (t < TPB * 32) {
        unsigned* dst = kside ? minB : minA;
        dst[ngrp * (TPB * 32) + t] = minarr[t];
    }

#pragma unroll
    for (int r = 0; r < 16; ++r) {
        float d = best_d[r];
        const unsigned nib = ((r < 8 ? nib0 : nib1) >> (4 * (r & 7))) & 0xFu;
        unsigned n = (unsigned)((tbase + (int)nib) * 32 + col);
        for (int off = 16; off >= 1; off >>= 1) {
            float od = __shfl_xor(d, off);
            unsigned on = __shfl_xor(n, off);
            bool take = (od < d) || (od == d && on < n);
            d = take ? od : d;
            n = take ? on : n;
        }
        if (col == 0) {
            int k = kbase + (r & 3) + 8 * (r >> 2) + 4 * half;
            unsigned long long p =
                ((unsigned long long)__float_as_uint(d + 1024.f) << 32) |
                (unsigned long long)n;
            atomicMin(&pack[k], p);
        }
    }
}

__global__ void finalize1(const float* __restrict__ centers,
                          const unsigned long long* __restrict__ pack,
                          const unsigned* __restrict__ minA,
                          const unsigned* __restrict__ minB,
                          float* __restrict__ lossPartial,
                          float* __restrict__ out) {
    __shared__ float wsum[8];
    const int t = threadIdx.x, wv = t >> 6, ln = t & 63;
    const int gid = blockIdx.x * 512 + t;
    if (gid < 16384)
        reinterpret_cast<float4*>(out)[gid] =
            reinterpret_cast<const float4*>(centers)[gid];
    if (gid < K_C)
        out[65536 + gid] = (float)(unsigned)(pack[gid] & 0xFFFFFFFFu);
    float s = 0.f;
    if (gid < N_EMB) {
        float m = fminf(__uint_as_float(minA[gid]), __uint_as_float(minB[gid]));
        s = sqrtf(fmaxf(m, 1e-12f));
    }
#pragma unroll
    for (int off = 1; off < 64; off <<= 1) s += __shfl_xor(s, off);
    if (ln == 0) wsum[wv] = s;
    __syncthreads();
    if (t == 0) {
        float tot = 0.f;
#pragma unroll
        for (int i = 0; i < 8; ++i) tot += wsum[i];
        lossPartial[blockIdx.x] = tot;
    }
}

__global__ void finalize2(const float* __restrict__ lossPartial,
                          float* __restrict__ out) {
    __shared__ float wsum[8];
    const int t = threadIdx.x, wv = t >> 6, ln = t & 63;
    float s = (t < 391) ? lossPartial[t] : 0.f;
#pragma unroll
    for (int off = 1; off < 64; off <<= 1) s += __shfl_xor(s, off);
    if (ln == 0) wsum[wv] = s;
    __syncthreads();
    if (t == 0) {
        float tot = 0.f;
#pragma unroll
        for (int i = 0; i < 8; ++i) tot += wsum[i];
        out[65536 + K_C] = tot;
    }
}

extern "C" void kernel_launch(void* const* d_in, const int* in_sizes, int n_in,
                              void* d_out, int out_size, void* d_ws, size_t ws_size,
                              hipStream_t stream) {
    float* embs_rw       = (float*)d_in[0];          // converted in place each launch
    const float* centers = (const float*)d_in[1];
    float* out = (float*)d_out;

    unsigned long long* pack = (unsigned long long*)d_ws;
    unsigned short* hiA = (unsigned short*)((char*)d_ws + 4096);
    unsigned short* loA = (unsigned short*)((char*)d_ws + 151552);
    float* x2g = (float*)((char*)d_ws + 282624);
    unsigned* minA = (unsigned*)((char*)d_ws + 1082624);
    unsigned* minB = (unsigned*)((char*)d_ws + 1882624);
    float* lossPartial = (float*)((char*)d_ws + 2682624);

    prep_b<<<6250, 512, 0, stream>>>(embs_rw, x2g);
    init_kernel<<<64, 512, 0, stream>>>(centers, hiA, loA, pack);
    cluster_mfma<<<NGRPS * 2, 512, 0, stream>>>((const float*)embs_rw, hiA, loA,
                                                x2g, pack, minA, minB);
    finalize1<<<391, 512, 0, stream>>>(centers, pack, minA, minB, lossPartial, out);
    finalize2<<<1, 512, 0, stream>>>(lossPartial, out);
}